// Round 2
// baseline (456.230 us; speedup 1.0000x reference)
//
#include <hip/hip_runtime.h>

typedef unsigned short u16;
typedef __attribute__((ext_vector_type(4))) float f32x4;
typedef __attribute__((ext_vector_type(8))) short short8;
typedef __attribute__((ext_vector_type(4))) unsigned short u16x4;
typedef __attribute__((ext_vector_type(8))) unsigned short u16x8;

__device__ __forceinline__ float clampf(float x, float lo, float hi){ return fminf(fmaxf(x, lo), hi); }
// fixed-point quantizers (round half-to-even like jnp.round)
__device__ __forceinline__ float qz44i(float x){ return clampf(rintf(x*16.f), -128.f, 127.f); }      // integer value
__device__ __forceinline__ float qz44v(float x){ return qz44i(x)*0.0625f; }                          // dequant value
__device__ __forceinline__ float qz87v(float x){ return clampf(rintf(x*128.f), -128.f, 127.f)*0.0078125f; }
// exact bf16 bits for values already representable in bf16 (all quantized values are)
__device__ __forceinline__ u16 bfbits(float f){ return (u16)(__float_as_uint(f) >> 16); }

__device__ __forceinline__ void gll16(const void* g, void* l){
  __builtin_amdgcn_global_load_lds((const __attribute__((address_space(1))) void*)g,
                                   (__attribute__((address_space(3))) void*)l, 16, 0, 0);
}

// ---------------- weight quantize (all 5 weights, one launch): fp32 -> qz(.,8,7) bf16 ----------------
// segments (in 4-elem vectors): q 256K, kv 512K, pj 256K, f1 1M, f2 1M  => total 3M vectors
__global__ __launch_bounds__(256) void kquantw5(const float* __restrict__ w0, u16* __restrict__ o0,
                                                const float* __restrict__ w1, u16* __restrict__ o1,
                                                const float* __restrict__ w2, u16* __restrict__ o2,
                                                const float* __restrict__ w3, u16* __restrict__ o3,
                                                const float* __restrict__ w4, u16* __restrict__ o4){
  int v = blockIdx.x*256 + threadIdx.x;      // vector index, 0..3M-1
  const float* w; u16* o; int base;
  if      (v <  262144){ w = w0; o = o0; base = 0;       }
  else if (v <  786432){ w = w1; o = o1; base = 262144;  }
  else if (v < 1048576){ w = w2; o = o2; base = 786432;  }
  else if (v < 2097152){ w = w3; o = o3; base = 1048576; }
  else                 { w = w4; o = o4; base = 2097152; }
  int i = (v - base)*4;
  float4 val = *(const float4*)(w + i);
  u16x4 r;
  r.x = bfbits(qz87v(val.x)); r.y = bfbits(qz87v(val.y));
  r.z = bfbits(qz87v(val.z)); r.w = bfbits(qz87v(val.w));
  *(u16x4*)(o + i) = r;
}

// ---------------- affine + quantize: h = qz( qz(qz(x)*qz(w)) + qz(b) ) bf16 ----------------
__global__ __launch_bounds__(256) void kaffine(const float* __restrict__ x, const float* __restrict__ aw,
                                               const float* __restrict__ ab, u16* __restrict__ o, int n){
  int i = (blockIdx.x*256 + threadIdx.x)*4;
  if (i >= n) return;
  float awv = qz44v(aw[0]);
  float abi = qz44i(ab[0]);   // integer
  float4 v = *(const float4*)(x + i);
  float in[4] = {v.x, v.y, v.z, v.w};
  u16x4 r;
  #pragma unroll
  for (int k=0;k<4;++k){
    float t  = qz44v(in[k]) * awv;           // qz(x)*qz(w), exact fp32
    float hi = clampf(qz44i(t) + abi, -128.f, 127.f);   // qz(t)+qz(b) then consumer's qz(.,8,4) == clip
    ((u16*)&r)[k] = bfbits(hi*0.0625f);
  }
  *(u16x4*)(o + i) = r;
}

// ---------------- V transpose: KVb[b*1024+n][1024+h*64+d] -> VT[bh][d][n] ----------------
__global__ __launch_bounds__(256) void ktransv(const u16* __restrict__ KVb, u16* __restrict__ VT){
  __shared__ u16 t[64][72];
  int nt = blockIdx.x;       // n-tile 0..15
  int bh = blockIdx.y;       // 0..63
  int b = bh >> 4, h = bh & 15;
  int tid = threadIdx.x;
  int nl = tid >> 2, d0 = (tid & 3)*16;
  const u16* src = KVb + (size_t)(b*1024 + nt*64 + nl)*2048 + 1024 + h*64 + d0;
  u16x8 v0 = *(const u16x8*)(src);
  u16x8 v1 = *(const u16x8*)(src + 8);
  #pragma unroll
  for (int k=0;k<8;++k) t[nl][d0+k]   = ((u16*)&v0)[k];
  #pragma unroll
  for (int k=0;k<8;++k) t[nl][d0+8+k] = ((u16*)&v1)[k];
  __syncthreads();
  int dl = tid >> 2, n0 = (tid & 3)*16;
  u16x8 o0, o1;
  #pragma unroll
  for (int k=0;k<8;++k) ((u16*)&o0)[k] = t[n0+k][dl];
  #pragma unroll
  for (int k=0;k<8;++k) ((u16*)&o1)[k] = t[n0+8+k][dl];
  u16* dst = VT + (size_t)bh*65536 + (size_t)dl*1024 + nt*64 + n0;
  *(u16x8*)(dst)     = o0;
  *(u16x8*)(dst + 8) = o1;
}

// ---------------- GEMM: Y = A(bf16,q) @ Bw(bf16,q)^T, templated epilogue ----------------
// EPI 0: store bf16(qz44(y))                        (q / kv GEMMs)
// EPI 1: y+=qz87(bias); outF = qz44(extra)+qz44(y)  (proj -> x1 fp32)
// EPI 2: y+=qz87(bias); relu; store bf16(qz44(y))   (fc1 -> mq)
// EPI 3: y+=qz87(bias); outF = qz44(extra)+qz44(y)  (fc2 -> out fp32)
template<int EPI>
__global__ __launch_bounds__(256) void kgemm(
    const u16* __restrict__ A, const u16* __restrict__ Bw,
    const float* __restrict__ bias, const float* __restrict__ extra,
    u16* __restrict__ outB, float* __restrict__ outF,
    int M, int N, int K)
{
  __shared__ char As[128*64*2];
  __shared__ char Bs[128*64*2];
  const int tid = threadIdx.x, lane = tid & 63, w = tid >> 6;
  const int bm = blockIdx.y*128, bn = blockIdx.x*128;
  const int wr = (w>>1)*64, wc = (w&1)*64;
  const int srow = lane>>3;
  const int scol = (((lane&7) ^ srow) & 7)*8;     // pre-swizzled source column (elems)
  const int mrow = lane & 15, kg = lane >> 4, swz = (lane & 7) << 4;

  const u16* Ab = A  + (size_t)bm*K;
  const u16* Bb = Bw + (size_t)bn*K;

  f32x4 acc[4][4];
  #pragma unroll
  for (int i=0;i<4;++i)
    #pragma unroll
    for (int j=0;j<4;++j) acc[i][j] = (f32x4){0.f,0.f,0.f,0.f};

  for (int k0 = 0; k0 < K; k0 += 64){
    #pragma unroll
    for (int c=0;c<4;++c){
      int ch = w*4 + c;
      int row = ch*8 + srow;
      gll16(Ab + (size_t)row*K + k0 + scol, As + ch*1024);
      gll16(Bb + (size_t)row*K + k0 + scol, Bs + ch*1024);
    }
    __syncthreads();
    #pragma unroll
    for (int ks=0; ks<2; ++ks){
      const int cb = (64*ks + 16*kg) ^ swz;
      short8 av[4], bv[4];
      #pragma unroll
      for (int i=0;i<4;++i) av[i] = *(const short8*)(As + (wr + i*16 + mrow)*128 + cb);
      #pragma unroll
      for (int j=0;j<4;++j) bv[j] = *(const short8*)(Bs + (wc + j*16 + mrow)*128 + cb);
      #pragma unroll
      for (int i=0;i<4;++i)
        #pragma unroll
        for (int j=0;j<4;++j)
          acc[i][j] = __builtin_amdgcn_mfma_f32_16x16x32_bf16(av[i], bv[j], acc[i][j], 0, 0, 0);
    }
    __syncthreads();
  }

  #pragma unroll
  for (int i=0;i<4;++i){
    #pragma unroll
    for (int j=0;j<4;++j){
      #pragma unroll
      for (int r=0;r<4;++r){
        int row = bm + wr + i*16 + 4*kg + r;
        int col = bn + wc + j*16 + mrow;
        float y = acc[i][j][r];
        size_t idx = (size_t)row*N + col;
        if (EPI == 0){
          outB[idx] = bfbits(qz44v(y));
        } else if (EPI == 1){
          y += qz87v(bias[col]);
          outF[idx] = qz44v(extra[idx]) + qz44v(y);
        } else if (EPI == 2){
          y += qz87v(bias[col]);
          y = fmaxf(y, 0.f);
          outB[idx] = bfbits(qz44v(y));
        } else {
          y += qz87v(bias[col]);
          outF[idx] = qz44v(extra[idx]) + qz44v(y);
        }
      }
    }
  }
}

// ---------------- fused quantized attention (two-pass softmax) ----------------
__device__ __forceinline__ void compute_s(const char* Qs, const char* Ks,
                                          int w, int mrow, int kg, int swz, f32x4 (&s)[2][8]){
  short8 a[2][2];
  #pragma unroll
  for (int i=0;i<2;++i)
    #pragma unroll
    for (int ks=0;ks<2;++ks)
      a[i][ks] = *(const short8*)(Qs + (w*32 + i*16 + mrow)*128 + ((64*ks + 16*kg) ^ swz));
  #pragma unroll
  for (int i=0;i<2;++i)
    #pragma unroll
    for (int jf=0;jf<8;++jf) s[i][jf] = (f32x4){0.f,0.f,0.f,0.f};
  #pragma unroll
  for (int jf=0;jf<8;++jf){
    short8 b0 = *(const short8*)(Ks + (jf*16 + mrow)*128 + ((16*kg) ^ swz));
    short8 b1 = *(const short8*)(Ks + (jf*16 + mrow)*128 + ((64 + 16*kg) ^ swz));
    #pragma unroll
    for (int i=0;i<2;++i){
      s[i][jf] = __builtin_amdgcn_mfma_f32_16x16x32_bf16(a[i][0], b0, s[i][jf], 0, 0, 0);
      s[i][jf] = __builtin_amdgcn_mfma_f32_16x16x32_bf16(a[i][1], b1, s[i][jf], 0, 0, 0);
    }
  }
}

__global__ __launch_bounds__(256) void kattn(const u16* __restrict__ Qb, const u16* __restrict__ KVb,
                                             const u16* __restrict__ VT, u16* __restrict__ zq)
{
  __shared__ char Qs[128*128];
  __shared__ char Ks[128*128];
  __shared__ char Ps[128*256];
  __shared__ char Vs[64*256];
  const int tid = threadIdx.x, lane = tid & 63, w = tid >> 6;
  const int qt = blockIdx.x, bh = blockIdx.y;
  const int b = bh >> 4, h = bh & 15;
  const int srow = lane >> 3;
  const int scol = (((lane&7) ^ srow) & 7)*8;
  const int mrow = lane & 15, kg = lane >> 4, swz = (lane & 7) << 4;
  const size_t q0 = (size_t)(b*1024 + qt*128);

  // stage Q once
  #pragma unroll
  for (int c=0;c<4;++c){
    int ch = w*4 + c; int r = ch*8 + srow;
    gll16(Qb + (q0 + r)*1024 + h*64 + scol, Qs + ch*1024);
  }

  float m[2][4], Z[2][4];
  #pragma unroll
  for (int i=0;i<2;++i)
    #pragma unroll
    for (int r=0;r<4;++r){ m[i][r] = -3.0e38f; Z[i][r] = 0.f; }

  // ---- pass 1: row max + denom over quantized logits ----
  for (int kt=0; kt<8; ++kt){
    #pragma unroll
    for (int c=0;c<4;++c){
      int ch = w*4 + c; int r = ch*8 + srow;
      gll16(KVb + (size_t)(b*1024 + kt*128 + r)*2048 + h*64 + scol, Ks + ch*1024);
    }
    __syncthreads();
    f32x4 s[2][8];
    compute_s(Qs, Ks, w, mrow, kg, swz, s);
    #pragma unroll
    for (int i=0;i<2;++i){
      #pragma unroll
      for (int r=0;r<4;++r){
        float lv[8];
        float tmax = -3.0e38f;
        #pragma unroll
        for (int jf=0;jf<8;++jf){
          lv[jf] = clampf(rintf(s[i][jf][r]*2.f), -128.f, 127.f)*0.0625f;  // qz44(S*1/8)
          tmax = fmaxf(tmax, lv[jf]);
        }
        #pragma unroll
        for (int off=1; off<16; off<<=1) tmax = fmaxf(tmax, __shfl_xor(tmax, off));
        float ts = 0.f;
        #pragma unroll
        for (int jf=0;jf<8;++jf) ts += expf(lv[jf] - tmax);
        #pragma unroll
        for (int off=1; off<16; off<<=1) ts += __shfl_xor(ts, off);
        float mo = m[i][r];
        float mn = fmaxf(mo, tmax);
        Z[i][r] = Z[i][r]*expf(mo - mn) + ts*expf(tmax - mn);
        m[i][r] = mn;
      }
    }
    __syncthreads();
  }

  // ---- pass 2: P = qz(exp(l-m)/Z, 8,7) -> PV ----
  f32x4 zacc[2][4];
  #pragma unroll
  for (int i=0;i<2;++i)
    #pragma unroll
    for (int d=0;d<4;++d) zacc[i][d] = (f32x4){0.f,0.f,0.f,0.f};

  for (int kt=0; kt<8; ++kt){
    #pragma unroll
    for (int c=0;c<4;++c){
      int ch = w*4 + c; int r = ch*8 + srow;
      gll16(KVb + (size_t)(b*1024 + kt*128 + r)*2048 + h*64 + scol, Ks + ch*1024);
    }
    #pragma unroll
    for (int c=0;c<4;++c){
      int ch = w*4 + c; int dr = ch*4 + kg;
      int vx = ((lane&15) ^ (dr & 7))*8;
      gll16(VT + (size_t)bh*65536 + (size_t)dr*1024 + kt*128 + vx, Vs + ch*1024);
    }
    __syncthreads();
    f32x4 s[2][8];
    compute_s(Qs, Ks, w, mrow, kg, swz, s);
    #pragma unroll
    for (int i=0;i<2;++i){
      #pragma unroll
      for (int r=0;r<4;++r){
        float mm = m[i][r], zz = Z[i][r];
        int prow = w*32 + i*16 + 4*kg + r;
        int sw2 = (prow & 7) << 4;
        #pragma unroll
        for (int jf=0;jf<8;++jf){
          float lv = clampf(rintf(s[i][jf][r]*2.f), -128.f, 127.f)*0.0625f;
          float p = expf(lv - mm) / zz;
          float pi = fminf(rintf(p*128.f), 127.f);
          *(u16*)(Ps + prow*256 + (((jf*16 + mrow)*2) ^ sw2)) = bfbits(pi*0.0078125f);
        }
      }
    }
    __syncthreads();
    #pragma unroll
    for (int ms=0; ms<4; ++ms){
      const int cb = (64*ms + 16*kg) ^ swz;
      short8 pa0 = *(const short8*)(Ps + (w*32 +  0 + mrow)*256 + cb);
      short8 pa1 = *(const short8*)(Ps + (w*32 + 16 + mrow)*256 + cb);
      #pragma unroll
      for (int df=0; df<4; ++df){
        short8 vb = *(const short8*)(Vs + (df*16 + mrow)*256 + cb);
        zacc[0][df] = __builtin_amdgcn_mfma_f32_16x16x32_bf16(pa0, vb, zacc[0][df], 0, 0, 0);
        zacc[1][df] = __builtin_amdgcn_mfma_f32_16x16x32_bf16(pa1, vb, zacc[1][df], 0, 0, 0);
      }
    }
    __syncthreads();
  }

  // epilogue: z quantized (8,4) bf16, layout [b,n, h*64+d]
  #pragma unroll
  for (int i=0;i<2;++i){
    #pragma unroll
    for (int df=0; df<4; ++df){
      #pragma unroll
      for (int r=0;r<4;++r){
        int row = qt*128 + w*32 + i*16 + 4*kg + r;
        int col = df*16 + mrow;
        zq[((size_t)b*1024 + row)*1024 + h*64 + col] = bfbits(qz44v(zacc[i][df][r]));
      }
    }
  }
}

// ---------------- launcher ----------------
extern "C" void kernel_launch(void* const* d_in, const int* in_sizes, int n_in,
                              void* d_out, int out_size, void* d_ws, size_t ws_size,
                              hipStream_t stream) {
  const float* x      = (const float*)d_in[0];
  const float* q_w    = (const float*)d_in[1];
  const float* kv_w   = (const float*)d_in[2];
  const float* proj_w = (const float*)d_in[3];
  const float* proj_b = (const float*)d_in[4];
  const float* fc1_w  = (const float*)d_in[5];
  const float* fc1_b  = (const float*)d_in[6];
  const float* fc2_w  = (const float*)d_in[7];
  const float* fc2_b  = (const float*)d_in[8];
  const float* aff1_w = (const float*)d_in[9];
  const float* aff1_b = (const float*)d_in[10];
  const float* aff2_w = (const float*)d_in[11];
  const float* aff2_b = (const float*)d_in[12];

  char* ws = (char*)d_ws;
  const size_t MB = 1u << 20;
  u16*   wq_q  = (u16*)(ws + 0*MB);     // 2MB
  u16*   wq_kv = (u16*)(ws + 2*MB);     // 4MB
  u16*   wq_pj = (u16*)(ws + 6*MB);     // 2MB
  u16*   wq_f1 = (u16*)(ws + 8*MB);     // 8MB
  u16*   wq_f2 = (u16*)(ws + 16*MB);    // 8MB
  float* x1    = (float*)(ws + 24*MB);  // 16MB fp32
  u16*   h1q   = (u16*)(ws + 40*MB);    // 8MB  (reused as zq)
  u16*   Qbuf  = (u16*)(ws + 48*MB);    // 8MB  (reused as h2q)
  u16*   KVb   = (u16*)(ws + 56*MB);    // 16MB
  u16*   VT    = (u16*)(ws + 72*MB);    // 8MB
  u16*   mq    = (u16*)(ws + 56*MB);    // 32MB, overlaps KVb+VT (dead by fc1)
  u16*   zq    = h1q;
  u16*   h2q   = Qbuf;

  // quantize all weights, one launch (12M elems / 4 per thread / 256 per block)
  kquantw5<<<12288, 256, 0, stream>>>(q_w, wq_q, kv_w, wq_kv, proj_w, wq_pj,
                                      fc1_w, wq_f1, fc2_w, wq_f2);

  // attention branch
  kaffine<<<4096, 256, 0, stream>>>(x, aff1_w, aff1_b, h1q, 4096*1024);
  kgemm<0><<<dim3(8,32),  256, 0, stream>>>(h1q, wq_q,  nullptr, nullptr, Qbuf, nullptr, 4096, 1024, 1024);
  kgemm<0><<<dim3(16,32), 256, 0, stream>>>(h1q, wq_kv, nullptr, nullptr, KVb,  nullptr, 4096, 2048, 1024);
  ktransv<<<dim3(16,64), 256, 0, stream>>>(KVb, VT);
  kattn<<<dim3(8,64), 256, 0, stream>>>(Qbuf, KVb, VT, zq);
  kgemm<1><<<dim3(8,32),  256, 0, stream>>>(zq, wq_pj, proj_b, x, nullptr, x1, 4096, 1024, 1024);

  // mlp branch
  kaffine<<<4096, 256, 0, stream>>>(x1, aff2_w, aff2_b, h2q, 4096*1024);
  kgemm<2><<<dim3(32,32), 256, 0, stream>>>(h2q, wq_f1, fc1_b, nullptr, mq, nullptr, 4096, 4096, 1024);
  kgemm<3><<<dim3(8,32),  256, 0, stream>>>(mq, wq_f2, fc2_b, x1, nullptr, (float*)d_out, 4096, 1024, 4096);
}

// Round 9
// 426.981 us; speedup vs baseline: 1.0685x; 1.0685x over previous
//
#include <hip/hip_runtime.h>

typedef unsigned short u16;
typedef __attribute__((ext_vector_type(4))) float f32x4;
typedef __attribute__((ext_vector_type(8))) short short8;
typedef __attribute__((ext_vector_type(4))) unsigned short u16x4;
typedef __attribute__((ext_vector_type(8))) unsigned short u16x8;

__device__ __forceinline__ float clampf(float x, float lo, float hi){ return fminf(fmaxf(x, lo), hi); }
// fixed-point quantizers (round half-to-even like jnp.round)
__device__ __forceinline__ float qz44i(float x){ return clampf(rintf(x*16.f), -128.f, 127.f); }      // integer value
__device__ __forceinline__ float qz44v(float x){ return qz44i(x)*0.0625f; }                          // dequant value
__device__ __forceinline__ float qz87v(float x){ return clampf(rintf(x*128.f), -128.f, 127.f)*0.0078125f; }
// exact bf16 bits for values already representable in bf16 (all quantized values are)
__device__ __forceinline__ u16 bfbits(float f){ return (u16)(__float_as_uint(f) >> 16); }

__device__ __forceinline__ void gll16(const void* g, void* l){
  __builtin_amdgcn_global_load_lds((const __attribute__((address_space(1))) void*)g,
                                   (__attribute__((address_space(3))) void*)l, 16, 0, 0);
}

// ---------------- weight quantize (all 5 weights, one launch): fp32 -> qz(.,8,7) bf16 ----------------
__global__ __launch_bounds__(256) void kquantw5(const float* __restrict__ w0, u16* __restrict__ o0,
                                                const float* __restrict__ w1, u16* __restrict__ o1,
                                                const float* __restrict__ w2, u16* __restrict__ o2,
                                                const float* __restrict__ w3, u16* __restrict__ o3,
                                                const float* __restrict__ w4, u16* __restrict__ o4){
  int v = blockIdx.x*256 + threadIdx.x;      // vector index, 0..3M-1
  const float* w; u16* o; int base;
  if      (v <  262144){ w = w0; o = o0; base = 0;       }
  else if (v <  786432){ w = w1; o = o1; base = 262144;  }
  else if (v < 1048576){ w = w2; o = o2; base = 786432;  }
  else if (v < 2097152){ w = w3; o = o3; base = 1048576; }
  else                 { w = w4; o = o4; base = 2097152; }
  int i = (v - base)*4;
  float4 val = *(const float4*)(w + i);
  u16x4 r;
  r.x = bfbits(qz87v(val.x)); r.y = bfbits(qz87v(val.y));
  r.z = bfbits(qz87v(val.z)); r.w = bfbits(qz87v(val.w));
  *(u16x4*)(o + i) = r;
}

// ---------------- affine + quantize: h = qz( qz(qz(x)*qz(w)) + qz(b) ) bf16 ----------------
__global__ __launch_bounds__(256) void kaffine(const float* __restrict__ x, const float* __restrict__ aw,
                                               const float* __restrict__ ab, u16* __restrict__ o, int n){
  int i = (blockIdx.x*256 + threadIdx.x)*4;
  if (i >= n) return;
  float awv = qz44v(aw[0]);
  float abi = qz44i(ab[0]);   // integer
  float4 v = *(const float4*)(x + i);
  float in[4] = {v.x, v.y, v.z, v.w};
  u16x4 r;
  #pragma unroll
  for (int k=0;k<4;++k){
    float t  = qz44v(in[k]) * awv;           // qz(x)*qz(w), exact fp32
    float hi = clampf(qz44i(t) + abi, -128.f, 127.f);   // qz(t)+qz(b) then consumer's qz(.,8,4) == clip
    ((u16*)&r)[k] = bfbits(hi*0.0625f);
  }
  *(u16x4*)(o + i) = r;
}

// ---------------- V transpose: KVb[b*1024+n][1024+h*64+d] -> VT[bh][d][n] ----------------
__global__ __launch_bounds__(256) void ktransv(const u16* __restrict__ KVb, u16* __restrict__ VT){
  __shared__ u16 t[64][72];
  int nt = blockIdx.x;       // n-tile 0..15
  int bh = blockIdx.y;       // 0..63
  int b = bh >> 4, h = bh & 15;
  int tid = threadIdx.x;
  int nl = tid >> 2, d0 = (tid & 3)*16;
  const u16* src = KVb + (size_t)(b*1024 + nt*64 + nl)*2048 + 1024 + h*64 + d0;
  u16x8 v0 = *(const u16x8*)(src);
  u16x8 v1 = *(const u16x8*)(src + 8);
  #pragma unroll
  for (int k=0;k<8;++k) t[nl][d0+k]   = ((u16*)&v0)[k];
  #pragma unroll
  for (int k=0;k<8;++k) t[nl][d0+8+k] = ((u16*)&v1)[k];
  __syncthreads();
  int dl = tid >> 2, n0 = (tid & 3)*16;
  u16x8 o0, o1;
  #pragma unroll
  for (int k=0;k<8;++k) ((u16*)&o0)[k] = t[n0+k][dl];
  #pragma unroll
  for (int k=0;k<8;++k) ((u16*)&o1)[k] = t[n0+8+k][dl];
  u16* dst = VT + (size_t)bh*65536 + (size_t)dl*1024 + nt*64 + n0;
  *(u16x8*)(dst)     = o0;
  *(u16x8*)(dst + 8) = o1;
}

// ---------------- GEMM 128x128: Y = A(bf16,q) @ Bw(bf16,q)^T ----------------
// EPI 0: store bf16(qz44(y))                        (kv GEMM)
// EPI 2: y+=qz87(bias); relu; store bf16(qz44(y))   (fc1 -> mq)
template<int EPI>
__global__ __launch_bounds__(256) void kgemm(
    const u16* __restrict__ A, const u16* __restrict__ Bw,
    const float* __restrict__ bias, const float* __restrict__ extra,
    u16* __restrict__ outB, float* __restrict__ outF,
    int M, int N, int K)
{
  __shared__ char As[128*64*2];
  __shared__ char Bs[128*64*2];
  const int tid = threadIdx.x, lane = tid & 63, w = tid >> 6;
  const int bm = blockIdx.y*128, bn = blockIdx.x*128;
  const int wr = (w>>1)*64, wc = (w&1)*64;
  const int srow = lane>>3;
  const int scol = (((lane&7) ^ srow) & 7)*8;     // pre-swizzled source column (elems)
  const int mrow = lane & 15, kg = lane >> 4, swz = (lane & 7) << 4;

  const u16* Ab = A  + (size_t)bm*K;
  const u16* Bb = Bw + (size_t)bn*K;

  f32x4 acc[4][4];
  #pragma unroll
  for (int i=0;i<4;++i)
    #pragma unroll
    for (int j=0;j<4;++j) acc[i][j] = (f32x4){0.f,0.f,0.f,0.f};

  for (int k0 = 0; k0 < K; k0 += 64){
    #pragma unroll
    for (int c=0;c<4;++c){
      int ch = w*4 + c;
      int row = ch*8 + srow;
      gll16(Ab + (size_t)row*K + k0 + scol, As + ch*1024);
      gll16(Bb + (size_t)row*K + k0 + scol, Bs + ch*1024);
    }
    __syncthreads();
    #pragma unroll
    for (int ks=0; ks<2; ++ks){
      const int cb = (64*ks + 16*kg) ^ swz;
      short8 av[4], bv[4];
      #pragma unroll
      for (int i=0;i<4;++i) av[i] = *(const short8*)(As + (wr + i*16 + mrow)*128 + cb);
      #pragma unroll
      for (int j=0;j<4;++j) bv[j] = *(const short8*)(Bs + (wc + j*16 + mrow)*128 + cb);
      #pragma unroll
      for (int i=0;i<4;++i)
        #pragma unroll
        for (int j=0;j<4;++j)
          acc[i][j] = __builtin_amdgcn_mfma_f32_16x16x32_bf16(av[i], bv[j], acc[i][j], 0, 0, 0);
    }
    __syncthreads();
  }

  #pragma unroll
  for (int i=0;i<4;++i){
    #pragma unroll
    for (int j=0;j<4;++j){
      #pragma unroll
      for (int r=0;r<4;++r){
        int row = bm + wr + i*16 + 4*kg + r;
        int col = bn + wc + j*16 + mrow;
        float y = acc[i][j][r];
        size_t idx = (size_t)row*N + col;
        if (EPI == 0){
          outB[idx] = bfbits(qz44v(y));
        } else if (EPI == 1){
          y += qz87v(bias[col]);
          outF[idx] = qz44v(extra[idx]) + qz44v(y);
        } else if (EPI == 2){
          y += qz87v(bias[col]);
          y = fmaxf(y, 0.f);
          outB[idx] = bfbits(qz44v(y));
        } else {
          y += qz87v(bias[col]);
          outF[idx] = qz44v(extra[idx]) + qz44v(y);
        }
      }
    }
  }
}

// ---------------- GEMM 128x64 (for N=1024 GEMMs: q / proj / fc2 — 512 blocks, 2+/CU) ----------------
template<int EPI>
__global__ __launch_bounds__(256) void kgemm64(
    const u16* __restrict__ A, const u16* __restrict__ Bw,
    const float* __restrict__ bias, const float* __restrict__ extra,
    u16* __restrict__ outB, float* __restrict__ outF,
    int M, int N, int K)
{
  __shared__ char As[128*64*2];   // 16KB
  __shared__ char Bs[64*64*2];    // 8KB
  const int tid = threadIdx.x, lane = tid & 63, w = tid >> 6;
  const int bm = blockIdx.y*128, bn = blockIdx.x*64;
  const int wr = w*32;
  const int srow = lane>>3;
  const int scol = (((lane&7) ^ srow) & 7)*8;
  const int mrow = lane & 15, kg = lane >> 4, swz = (lane & 7) << 4;

  const u16* Ab = A  + (size_t)bm*K;
  const u16* Bb = Bw + (size_t)bn*K;

  f32x4 acc[2][4];
  #pragma unroll
  for (int i=0;i<2;++i)
    #pragma unroll
    for (int j=0;j<4;++j) acc[i][j] = (f32x4){0.f,0.f,0.f,0.f};

  for (int k0 = 0; k0 < K; k0 += 64){
    #pragma unroll
    for (int c=0;c<4;++c){
      int ch = w*4 + c;
      int row = ch*8 + srow;
      gll16(Ab + (size_t)row*K + k0 + scol, As + ch*1024);
    }
    #pragma unroll
    for (int c=0;c<2;++c){
      int ch = w*2 + c;
      int row = ch*8 + srow;
      gll16(Bb + (size_t)row*K + k0 + scol, Bs + ch*1024);
    }
    __syncthreads();
    #pragma unroll
    for (int ks=0; ks<2; ++ks){
      const int cb = (64*ks + 16*kg) ^ swz;
      short8 av[2], bv[4];
      #pragma unroll
      for (int i=0;i<2;++i) av[i] = *(const short8*)(As + (wr + i*16 + mrow)*128 + cb);
      #pragma unroll
      for (int j=0;j<4;++j) bv[j] = *(const short8*)(Bs + (j*16 + mrow)*128 + cb);
      #pragma unroll
      for (int i=0;i<2;++i)
        #pragma unroll
        for (int j=0;j<4;++j)
          acc[i][j] = __builtin_amdgcn_mfma_f32_16x16x32_bf16(av[i], bv[j], acc[i][j], 0, 0, 0);
    }
    __syncthreads();
  }

  #pragma unroll
  for (int i=0;i<2;++i){
    #pragma unroll
    for (int j=0;j<4;++j){
      #pragma unroll
      for (int r=0;r<4;++r){
        int row = bm + wr + i*16 + 4*kg + r;
        int col = bn + j*16 + mrow;
        float y = acc[i][j][r];
        size_t idx = (size_t)row*N + col;
        if (EPI == 0){
          outB[idx] = bfbits(qz44v(y));
        } else if (EPI == 1){
          y += qz87v(bias[col]);
          outF[idx] = qz44v(extra[idx]) + qz44v(y);
        } else if (EPI == 2){
          y += qz87v(bias[col]);
          y = fmaxf(y, 0.f);
          outB[idx] = bfbits(qz44v(y));
        } else {
          y += qz87v(bias[col]);
          outF[idx] = qz44v(extra[idx]) + qz44v(y);
        }
      }
    }
  }
}

// ---------------- fused quantized attention (two-pass softmax, LUT exp) ----------------
__device__ __forceinline__ void compute_s(const char* Qs, const char* Ks,
                                          int w, int mrow, int kg, int swz, f32x4 (&s)[2][8]){
  short8 a[2][2];
  #pragma unroll
  for (int i=0;i<2;++i)
    #pragma unroll
    for (int ks=0;ks<2;++ks)
      a[i][ks] = *(const short8*)(Qs + (w*32 + i*16 + mrow)*128 + ((64*ks + 16*kg) ^ swz));
  #pragma unroll
  for (int i=0;i<2;++i)
    #pragma unroll
    for (int jf=0;jf<8;++jf) s[i][jf] = (f32x4){0.f,0.f,0.f,0.f};
  #pragma unroll
  for (int jf=0;jf<8;++jf){
    short8 b0 = *(const short8*)(Ks + (jf*16 + mrow)*128 + ((16*kg) ^ swz));
    short8 b1 = *(const short8*)(Ks + (jf*16 + mrow)*128 + ((64 + 16*kg) ^ swz));
    #pragma unroll
    for (int i=0;i<2;++i){
      s[i][jf] = __builtin_amdgcn_mfma_f32_16x16x32_bf16(a[i][0], b0, s[i][jf], 0, 0, 0);
      s[i][jf] = __builtin_amdgcn_mfma_f32_16x16x32_bf16(a[i][1], b1, s[i][jf], 0, 0, 0);
    }
  }
}

__global__ __launch_bounds__(256) void kattn(const u16* __restrict__ Qb, const u16* __restrict__ KVb,
                                             const u16* __restrict__ VT, u16* __restrict__ zq)
{
  __shared__ char Qs[128*128];    // 16KB
  __shared__ char Ks[128*128];    // 16KB
  __shared__ char Ps[128*256];    // 32KB
  __shared__ float exp_t[256];    // 1KB : exp_t[i] = expf(-i/16), bit-identical to prior expf path
  const int tid = threadIdx.x, lane = tid & 63, w = tid >> 6;
  const int qt = blockIdx.x, bh = blockIdx.y;
  const int b = bh >> 4, h = bh & 15;
  const int srow = lane >> 3;
  const int scol = (((lane&7) ^ srow) & 7)*8;
  const int mrow = lane & 15, kg = lane >> 4, swz = (lane & 7) << 4;
  const size_t q0 = (size_t)(b*1024 + qt*128);
  const u16* Vg = VT + (size_t)bh*65536;

  // build exp LUT (integer-logit domain: index i <-> exp((li - M)/16), i = M - li)
  exp_t[tid & 255] = expf(-(float)(tid & 255) * 0.0625f);

  // stage Q once
  #pragma unroll
  for (int c=0;c<4;++c){
    int ch = w*4 + c; int r = ch*8 + srow;
    gll16(Qb + (q0 + r)*1024 + h*64 + scol, Qs + ch*1024);
  }

  float m[2][4], Z[2][4];
  #pragma unroll
  for (int i=0;i<2;++i)
    #pragma unroll
    for (int r=0;r<4;++r){ m[i][r] = -128.f; Z[i][r] = 0.f; }   // integer-logit units

  // ---- pass 1: row max + denom over quantized logits (integer domain + LUT) ----
  for (int kt=0; kt<8; ++kt){
    #pragma unroll
    for (int c=0;c<4;++c){
      int ch = w*4 + c; int r = ch*8 + srow;
      gll16(KVb + (size_t)(b*1024 + kt*128 + r)*2048 + h*64 + scol, Ks + ch*1024);
    }
    __syncthreads();
    f32x4 s[2][8];
    compute_s(Qs, Ks, w, mrow, kg, swz, s);
    #pragma unroll
    for (int i=0;i<2;++i){
      #pragma unroll
      for (int r=0;r<4;++r){
        float li[8];
        float tm = -128.f;
        #pragma unroll
        for (int jf=0;jf<8;++jf){
          li[jf] = clampf(rintf(s[i][jf][r]*2.f), -128.f, 127.f);   // logit * 16, integer-valued
          tm = fmaxf(tm, li[jf]);
        }
        #pragma unroll
        for (int off=1; off<16; off<<=1) tm = fmaxf(tm, __shfl_xor(tm, off));
        float ts = 0.f;
        #pragma unroll
        for (int jf=0;jf<8;++jf) ts += exp_t[(int)(tm - li[jf])];
        #pragma unroll
        for (int off=1; off<16; off<<=1) ts += __shfl_xor(ts, off);
        float mo = m[i][r];
        float mn = fmaxf(mo, tm);
        Z[i][r] = Z[i][r]*exp_t[(int)(mn - mo)] + ts*exp_t[(int)(mn - tm)];
        m[i][r] = mn;
      }
    }
    __syncthreads();
  }

  // ---- pass 2: P = qz(exp(l-m)/Z, 8,7) -> PV (V read direct from L1/L2, no Vs) ----
  f32x4 zacc[2][4];
  #pragma unroll
  for (int i=0;i<2;++i)
    #pragma unroll
    for (int d=0;d<4;++d) zacc[i][d] = (f32x4){0.f,0.f,0.f,0.f};

  for (int kt=0; kt<8; ++kt){
    #pragma unroll
    for (int c=0;c<4;++c){
      int ch = w*4 + c; int r = ch*8 + srow;
      gll16(KVb + (size_t)(b*1024 + kt*128 + r)*2048 + h*64 + scol, Ks + ch*1024);
    }
    __syncthreads();
    f32x4 s[2][8];
    compute_s(Qs, Ks, w, mrow, kg, swz, s);
    #pragma unroll
    for (int i=0;i<2;++i){
      #pragma unroll
      for (int r=0;r<4;++r){
        float Mi = m[i][r], zz = Z[i][r];
        int prow = w*32 + i*16 + 4*kg + r;
        int sw2 = (prow & 7) << 4;
        #pragma unroll
        for (int jf=0;jf<8;++jf){
          float li = clampf(rintf(s[i][jf][r]*2.f), -128.f, 127.f);
          float e = exp_t[(int)(Mi - li)];
          float p = e / zz;                                  // exact div (matches reference bits)
          float pi = fminf(rintf(p*128.f), 127.f);
          *(u16*)(Ps + prow*256 + (((jf*16 + mrow)*2) ^ sw2)) = bfbits(pi*0.0078125f);
        }
      }
    }
    // PV: each wave consumes only its own 32 P rows (same-wave LDS, no barrier needed)
    #pragma unroll
    for (int ms=0; ms<4; ++ms){
      const int cb = (64*ms + 16*kg) ^ swz;
      short8 pa0 = *(const short8*)(Ps + (w*32 +  0 + mrow)*256 + cb);
      short8 pa1 = *(const short8*)(Ps + (w*32 + 16 + mrow)*256 + cb);
      #pragma unroll
      for (int df=0; df<4; ++df){
        // V^T[d][k] fragment direct from global (unswizzled k = 32*ms + 8*kg)
        short8 vb = *(const short8*)(Vg + (size_t)(df*16 + mrow)*1024 + kt*128 + 32*ms + 8*kg);
        zacc[0][df] = __builtin_amdgcn_mfma_f32_16x16x32_bf16(pa0, vb, zacc[0][df], 0, 0, 0);
        zacc[1][df] = __builtin_amdgcn_mfma_f32_16x16x32_bf16(pa1, vb, zacc[1][df], 0, 0, 0);
      }
    }
    __syncthreads();
  }

  // epilogue: z quantized (8,4) bf16, layout [b,n, h*64+d]
  #pragma unroll
  for (int i=0;i<2;++i){
    #pragma unroll
    for (int df=0; df<4; ++df){
      #pragma unroll
      for (int r=0;r<4;++r){
        int row = qt*128 + w*32 + i*16 + 4*kg + r;
        int col = df*16 + mrow;
        zq[((size_t)b*1024 + row)*1024 + h*64 + col] = bfbits(qz44v(zacc[i][df][r]));
      }
    }
  }
}

// ---------------- launcher ----------------
extern "C" void kernel_launch(void* const* d_in, const int* in_sizes, int n_in,
                              void* d_out, int out_size, void* d_ws, size_t ws_size,
                              hipStream_t stream) {
  const float* x      = (const float*)d_in[0];
  const float* q_w    = (const float*)d_in[1];
  const float* kv_w   = (const float*)d_in[2];
  const float* proj_w = (const float*)d_in[3];
  const float* proj_b = (const float*)d_in[4];
  const float* fc1_w  = (const float*)d_in[5];
  const float* fc1_b  = (const float*)d_in[6];
  const float* fc2_w  = (const float*)d_in[7];
  const float* fc2_b  = (const float*)d_in[8];
  const float* aff1_w = (const float*)d_in[9];
  const float* aff1_b = (const float*)d_in[10];
  const float* aff2_w = (const float*)d_in[11];
  const float* aff2_b = (const float*)d_in[12];

  char* ws = (char*)d_ws;
  const size_t MB = 1u << 20;
  u16*   wq_q  = (u16*)(ws + 0*MB);     // 2MB
  u16*   wq_kv = (u16*)(ws + 2*MB);     // 4MB
  u16*   wq_pj = (u16*)(ws + 6*MB);     // 2MB
  u16*   wq_f1 = (u16*)(ws + 8*MB);     // 8MB
  u16*   wq_f2 = (u16*)(ws + 16*MB);    // 8MB
  float* x1    = (float*)(ws + 24*MB);  // 16MB fp32
  u16*   h1q   = (u16*)(ws + 40*MB);    // 8MB  (reused as zq)
  u16*   Qbuf  = (u16*)(ws + 48*MB);    // 8MB  (reused as h2q)
  u16*   KVb   = (u16*)(ws + 56*MB);    // 16MB
  u16*   VT    = (u16*)(ws + 72*MB);    // 8MB
  u16*   mq    = (u16*)(ws + 56*MB);    // 32MB, overlaps KVb+VT (dead by fc1)
  u16*   zq    = h1q;
  u16*   h2q   = Qbuf;

  // quantize all weights, one launch
  kquantw5<<<12288, 256, 0, stream>>>(q_w, wq_q, kv_w, wq_kv, proj_w, wq_pj,
                                      fc1_w, wq_f1, fc2_w, wq_f2);

  // attention branch
  kaffine<<<4096, 256, 0, stream>>>(x, aff1_w, aff1_b, h1q, 4096*1024);
  kgemm64<0><<<dim3(16,32), 256, 0, stream>>>(h1q, wq_q,  nullptr, nullptr, Qbuf, nullptr, 4096, 1024, 1024);
  kgemm<0><<<dim3(16,32),  256, 0, stream>>>(h1q, wq_kv, nullptr, nullptr, KVb,  nullptr, 4096, 2048, 1024);
  ktransv<<<dim3(16,64), 256, 0, stream>>>(KVb, VT);
  kattn<<<dim3(8,64), 256, 0, stream>>>(Qbuf, KVb, VT, zq);
  kgemm64<1><<<dim3(16,32), 256, 0, stream>>>(zq, wq_pj, proj_b, x, nullptr, x1, 4096, 1024, 1024);

  // mlp branch
  kaffine<<<4096, 256, 0, stream>>>(x1, aff2_w, aff2_b, h2q, 4096*1024);
  kgemm<2><<<dim3(32,32), 256, 0, stream>>>(h2q, wq_f1, fc1_b, nullptr, mq, nullptr, 4096, 4096, 1024);
  kgemm64<3><<<dim3(16,32), 256, 0, stream>>>(mq, wq_f2, fc2_b, x1, nullptr, (float*)d_out, 4096, 1024, 4096);
}

// Round 11
// 418.253 us; speedup vs baseline: 1.0908x; 1.0209x over previous
//
#include <hip/hip_runtime.h>

typedef unsigned short u16;
typedef __attribute__((ext_vector_type(4))) float f32x4;
typedef __attribute__((ext_vector_type(8))) short short8;
typedef __attribute__((ext_vector_type(4))) unsigned short u16x4;
typedef __attribute__((ext_vector_type(8))) unsigned short u16x8;

__device__ __forceinline__ float clampf(float x, float lo, float hi){ return fminf(fmaxf(x, lo), hi); }
// fixed-point quantizers (round half-to-even like jnp.round)
__device__ __forceinline__ float qz44i(float x){ return clampf(rintf(x*16.f), -128.f, 127.f); }      // integer value
__device__ __forceinline__ float qz44v(float x){ return qz44i(x)*0.0625f; }                          // dequant value
__device__ __forceinline__ float qz87v(float x){ return clampf(rintf(x*128.f), -128.f, 127.f)*0.0078125f; }
// exact bf16 bits for values already representable in bf16 (all quantized values are)
__device__ __forceinline__ u16 bfbits(float f){ return (u16)(__float_as_uint(f) >> 16); }

__device__ __forceinline__ void gll16(const void* g, void* l){
  __builtin_amdgcn_global_load_lds((const __attribute__((address_space(1))) void*)g,
                                   (__attribute__((address_space(3))) void*)l, 16, 0, 0);
}

// ---------------- weight quantize (all 5 weights, one launch): fp32 -> qz(.,8,7) bf16 ----------------
__global__ __launch_bounds__(256) void kquantw5(const float* __restrict__ w0, u16* __restrict__ o0,
                                                const float* __restrict__ w1, u16* __restrict__ o1,
                                                const float* __restrict__ w2, u16* __restrict__ o2,
                                                const float* __restrict__ w3, u16* __restrict__ o3,
                                                const float* __restrict__ w4, u16* __restrict__ o4){
  int v = blockIdx.x*256 + threadIdx.x;      // vector index, 0..3M-1
  const float* w; u16* o; int base;
  if      (v <  262144){ w = w0; o = o0; base = 0;       }
  else if (v <  786432){ w = w1; o = o1; base = 262144;  }
  else if (v < 1048576){ w = w2; o = o2; base = 786432;  }
  else if (v < 2097152){ w = w3; o = o3; base = 1048576; }
  else                 { w = w4; o = o4; base = 2097152; }
  int i = (v - base)*4;
  float4 val = *(const float4*)(w + i);
  u16x4 r;
  r.x = bfbits(qz87v(val.x)); r.y = bfbits(qz87v(val.y));
  r.z = bfbits(qz87v(val.z)); r.w = bfbits(qz87v(val.w));
  *(u16x4*)(o + i) = r;
}

// ---------------- affine + quantize: h = qz( qz(qz(x)*qz(w)) + qz(b) ) bf16 ----------------
__global__ __launch_bounds__(256) void kaffine(const float* __restrict__ x, const float* __restrict__ aw,
                                               const float* __restrict__ ab, u16* __restrict__ o, int n){
  int i = (blockIdx.x*256 + threadIdx.x)*4;
  if (i >= n) return;
  float awv = qz44v(aw[0]);
  float abi = qz44i(ab[0]);   // integer
  float4 v = *(const float4*)(x + i);
  float in[4] = {v.x, v.y, v.z, v.w};
  u16x4 r;
  #pragma unroll
  for (int k=0;k<4;++k){
    float t  = qz44v(in[k]) * awv;           // qz(x)*qz(w), exact fp32
    float hi = clampf(qz44i(t) + abi, -128.f, 127.f);   // qz(t)+qz(b) then consumer's qz(.,8,4) == clip
    ((u16*)&r)[k] = bfbits(hi*0.0625f);
  }
  *(u16x4*)(o + i) = r;
}

// ---------------- V transpose: KVb[b*1024+n][1024+h*64+d] -> VT[bh][d][n] ----------------
__global__ __launch_bounds__(256) void ktransv(const u16* __restrict__ KVb, u16* __restrict__ VT){
  __shared__ u16 t[64][72];
  int nt = blockIdx.x;       // n-tile 0..15
  int bh = blockIdx.y;       // 0..63
  int b = bh >> 4, h = bh & 15;
  int tid = threadIdx.x;
  int nl = tid >> 2, d0 = (tid & 3)*16;
  const u16* src = KVb + (size_t)(b*1024 + nt*64 + nl)*2048 + 1024 + h*64 + d0;
  u16x8 v0 = *(const u16x8*)(src);
  u16x8 v1 = *(const u16x8*)(src + 8);
  #pragma unroll
  for (int k=0;k<8;++k) t[nl][d0+k]   = ((u16*)&v0)[k];
  #pragma unroll
  for (int k=0;k<8;++k) t[nl][d0+8+k] = ((u16*)&v1)[k];
  __syncthreads();
  int dl = tid >> 2, n0 = (tid & 3)*16;
  u16x8 o0, o1;
  #pragma unroll
  for (int k=0;k<8;++k) ((u16*)&o0)[k] = t[n0+k][dl];
  #pragma unroll
  for (int k=0;k<8;++k) ((u16*)&o1)[k] = t[n0+8+k][dl];
  u16* dst = VT + (size_t)bh*65536 + (size_t)dl*1024 + nt*64 + n0;
  *(u16x8*)(dst)     = o0;
  *(u16x8*)(dst + 8) = o1;
}

// ---------------- GEMM 128x128: Y = A(bf16,q) @ Bw(bf16,q)^T ----------------
// EPI 0: store bf16(qz44(y))                        (kv GEMM)
// EPI 2: y+=qz87(bias); relu; store bf16(qz44(y))   (fc1 -> mq)
template<int EPI>
__global__ __launch_bounds__(256) void kgemm(
    const u16* __restrict__ A, const u16* __restrict__ Bw,
    const float* __restrict__ bias, const float* __restrict__ extra,
    u16* __restrict__ outB, float* __restrict__ outF,
    int M, int N, int K)
{
  __shared__ char As[128*64*2];
  __shared__ char Bs[128*64*2];
  const int tid = threadIdx.x, lane = tid & 63, w = tid >> 6;
  const int bm = blockIdx.y*128, bn = blockIdx.x*128;
  const int wr = (w>>1)*64, wc = (w&1)*64;
  const int srow = lane>>3;
  const int scol = (((lane&7) ^ srow) & 7)*8;     // pre-swizzled source column (elems)
  const int mrow = lane & 15, kg = lane >> 4, swz = (lane & 7) << 4;

  const u16* Ab = A  + (size_t)bm*K;
  const u16* Bb = Bw + (size_t)bn*K;

  f32x4 acc[4][4];
  #pragma unroll
  for (int i=0;i<4;++i)
    #pragma unroll
    for (int j=0;j<4;++j) acc[i][j] = (f32x4){0.f,0.f,0.f,0.f};

  for (int k0 = 0; k0 < K; k0 += 64){
    #pragma unroll
    for (int c=0;c<4;++c){
      int ch = w*4 + c;
      int row = ch*8 + srow;
      gll16(Ab + (size_t)row*K + k0 + scol, As + ch*1024);
      gll16(Bb + (size_t)row*K + k0 + scol, Bs + ch*1024);
    }
    __syncthreads();
    #pragma unroll
    for (int ks=0; ks<2; ++ks){
      const int cb = (64*ks + 16*kg) ^ swz;
      short8 av[4], bv[4];
      #pragma unroll
      for (int i=0;i<4;++i) av[i] = *(const short8*)(As + (wr + i*16 + mrow)*128 + cb);
      #pragma unroll
      for (int j=0;j<4;++j) bv[j] = *(const short8*)(Bs + (wc + j*16 + mrow)*128 + cb);
      #pragma unroll
      for (int i=0;i<4;++i)
        #pragma unroll
        for (int j=0;j<4;++j)
          acc[i][j] = __builtin_amdgcn_mfma_f32_16x16x32_bf16(av[i], bv[j], acc[i][j], 0, 0, 0);
    }
    __syncthreads();
  }

  #pragma unroll
  for (int i=0;i<4;++i){
    #pragma unroll
    for (int j=0;j<4;++j){
      #pragma unroll
      for (int r=0;r<4;++r){
        int row = bm + wr + i*16 + 4*kg + r;
        int col = bn + wc + j*16 + mrow;
        float y = acc[i][j][r];
        size_t idx = (size_t)row*N + col;
        if (EPI == 0){
          outB[idx] = bfbits(qz44v(y));
        } else if (EPI == 1){
          y += qz87v(bias[col]);
          outF[idx] = qz44v(extra[idx]) + qz44v(y);
        } else if (EPI == 2){
          y += qz87v(bias[col]);
          y = fmaxf(y, 0.f);
          outB[idx] = bfbits(qz44v(y));
        } else {
          y += qz87v(bias[col]);
          outF[idx] = qz44v(extra[idx]) + qz44v(y);
        }
      }
    }
  }
}

// ---------------- GEMM 128x64 (for N=1024 GEMMs: q / proj / fc2 — 512 blocks, 2+/CU) ----------------
template<int EPI>
__global__ __launch_bounds__(256) void kgemm64(
    const u16* __restrict__ A, const u16* __restrict__ Bw,
    const float* __restrict__ bias, const float* __restrict__ extra,
    u16* __restrict__ outB, float* __restrict__ outF,
    int M, int N, int K)
{
  __shared__ char As[128*64*2];   // 16KB
  __shared__ char Bs[64*64*2];    // 8KB
  const int tid = threadIdx.x, lane = tid & 63, w = tid >> 6;
  const int bm = blockIdx.y*128, bn = blockIdx.x*64;
  const int wr = w*32;
  const int srow = lane>>3;
  const int scol = (((lane&7) ^ srow) & 7)*8;
  const int mrow = lane & 15, kg = lane >> 4, swz = (lane & 7) << 4;

  const u16* Ab = A  + (size_t)bm*K;
  const u16* Bb = Bw + (size_t)bn*K;

  f32x4 acc[2][4];
  #pragma unroll
  for (int i=0;i<2;++i)
    #pragma unroll
    for (int j=0;j<4;++j) acc[i][j] = (f32x4){0.f,0.f,0.f,0.f};

  for (int k0 = 0; k0 < K; k0 += 64){
    #pragma unroll
    for (int c=0;c<4;++c){
      int ch = w*4 + c;
      int row = ch*8 + srow;
      gll16(Ab + (size_t)row*K + k0 + scol, As + ch*1024);
    }
    #pragma unroll
    for (int c=0;c<2;++c){
      int ch = w*2 + c;
      int row = ch*8 + srow;
      gll16(Bb + (size_t)row*K + k0 + scol, Bs + ch*1024);
    }
    __syncthreads();
    #pragma unroll
    for (int ks=0; ks<2; ++ks){
      const int cb = (64*ks + 16*kg) ^ swz;
      short8 av[2], bv[4];
      #pragma unroll
      for (int i=0;i<2;++i) av[i] = *(const short8*)(As + (wr + i*16 + mrow)*128 + cb);
      #pragma unroll
      for (int j=0;j<4;++j) bv[j] = *(const short8*)(Bs + (j*16 + mrow)*128 + cb);
      #pragma unroll
      for (int i=0;i<2;++i)
        #pragma unroll
        for (int j=0;j<4;++j)
          acc[i][j] = __builtin_amdgcn_mfma_f32_16x16x32_bf16(av[i], bv[j], acc[i][j], 0, 0, 0);
    }
    __syncthreads();
  }

  #pragma unroll
  for (int i=0;i<2;++i){
    #pragma unroll
    for (int j=0;j<4;++j){
      #pragma unroll
      for (int r=0;r<4;++r){
        int row = bm + wr + i*16 + 4*kg + r;
        int col = bn + j*16 + mrow;
        float y = acc[i][j][r];
        size_t idx = (size_t)row*N + col;
        if (EPI == 0){
          outB[idx] = bfbits(qz44v(y));
        } else if (EPI == 1){
          y += qz87v(bias[col]);
          outF[idx] = qz44v(extra[idx]) + qz44v(y);
        } else if (EPI == 2){
          y += qz87v(bias[col]);
          y = fmaxf(y, 0.f);
          outB[idx] = bfbits(qz44v(y));
        } else {
          y += qz87v(bias[col]);
          outF[idx] = qz44v(extra[idx]) + qz44v(y);
        }
      }
    }
  }
}

// ---------------- fused quantized attention (two-pass softmax, LUT exp, staged V) ----------------
__device__ __forceinline__ void compute_s(const char* Qs, const char* Ks,
                                          int w, int mrow, int kg, int swz, f32x4 (&s)[2][8]){
  short8 a[2][2];
  #pragma unroll
  for (int i=0;i<2;++i)
    #pragma unroll
    for (int ks=0;ks<2;++ks)
      a[i][ks] = *(const short8*)(Qs + (w*32 + i*16 + mrow)*128 + ((64*ks + 16*kg) ^ swz));
  #pragma unroll
  for (int i=0;i<2;++i)
    #pragma unroll
    for (int jf=0;jf<8;++jf) s[i][jf] = (f32x4){0.f,0.f,0.f,0.f};
  #pragma unroll
  for (int jf=0;jf<8;++jf){
    short8 b0 = *(const short8*)(Ks + (jf*16 + mrow)*128 + ((16*kg) ^ swz));
    short8 b1 = *(const short8*)(Ks + (jf*16 + mrow)*128 + ((64 + 16*kg) ^ swz));
    #pragma unroll
    for (int i=0;i<2;++i){
      s[i][jf] = __builtin_amdgcn_mfma_f32_16x16x32_bf16(a[i][0], b0, s[i][jf], 0, 0, 0);
      s[i][jf] = __builtin_amdgcn_mfma_f32_16x16x32_bf16(a[i][1], b1, s[i][jf], 0, 0, 0);
    }
  }
}

__global__ __launch_bounds__(256) void kattn(const u16* __restrict__ Qb, const u16* __restrict__ KVb,
                                             const u16* __restrict__ VT, u16* __restrict__ zq)
{
  __shared__ char Qs[128*128];    // 16KB
  __shared__ char Ks[128*128];    // 16KB
  __shared__ char Ps[128*256];    // 32KB
  __shared__ char Vs[64*128];     // 8KB : half of a V^T kt-tile, [64 d][64 n] u16, XOR-swizzled
  __shared__ float exp_t[256];    // 1KB : exp_t[i] = expf(-i/16)
  const int tid = threadIdx.x, lane = tid & 63, w = tid >> 6;
  const int qt = blockIdx.x, bh = blockIdx.y;
  const int b = bh >> 4, h = bh & 15;
  const int srow = lane >> 3;
  const int scol = (((lane&7) ^ srow) & 7)*8;
  const int mrow = lane & 15, kg = lane >> 4, swz = (lane & 7) << 4;
  const size_t q0 = (size_t)(b*1024 + qt*128);
  const u16* Vg = VT + (size_t)bh*65536;

  // build exp LUT (integer-logit domain: index i <-> exp((li - M)/16), i = M - li)
  exp_t[tid & 255] = expf(-(float)(tid & 255) * 0.0625f);

  // stage Q once
  #pragma unroll
  for (int c=0;c<4;++c){
    int ch = w*4 + c; int r = ch*8 + srow;
    gll16(Qb + (q0 + r)*1024 + h*64 + scol, Qs + ch*1024);
  }

  float m[2][4], Z[2][4];
  #pragma unroll
  for (int i=0;i<2;++i)
    #pragma unroll
    for (int r=0;r<4;++r){ m[i][r] = -128.f; Z[i][r] = 0.f; }   // integer-logit units

  // ---- pass 1: row max + denom over quantized logits (integer domain + LUT) ----
  for (int kt=0; kt<8; ++kt){
    #pragma unroll
    for (int c=0;c<4;++c){
      int ch = w*4 + c; int r = ch*8 + srow;
      gll16(KVb + (size_t)(b*1024 + kt*128 + r)*2048 + h*64 + scol, Ks + ch*1024);
    }
    __syncthreads();
    f32x4 s[2][8];
    compute_s(Qs, Ks, w, mrow, kg, swz, s);
    #pragma unroll
    for (int i=0;i<2;++i){
      #pragma unroll
      for (int r=0;r<4;++r){
        float li[8];
        float tm = -128.f;
        #pragma unroll
        for (int jf=0;jf<8;++jf){
          li[jf] = clampf(rintf(s[i][jf][r]*2.f), -128.f, 127.f);   // logit * 16, integer-valued
          tm = fmaxf(tm, li[jf]);
        }
        #pragma unroll
        for (int off=1; off<16; off<<=1) tm = fmaxf(tm, __shfl_xor(tm, off));
        float ts = 0.f;
        #pragma unroll
        for (int jf=0;jf<8;++jf) ts += exp_t[(int)(tm - li[jf])];
        #pragma unroll
        for (int off=1; off<16; off<<=1) ts += __shfl_xor(ts, off);
        float mo = m[i][r];
        float mn = fmaxf(mo, tm);
        Z[i][r] = Z[i][r]*exp_t[(int)(mn - mo)] + ts*exp_t[(int)(mn - tm)];
        m[i][r] = mn;
      }
    }
    __syncthreads();
  }

  // ---- pass 2: P = qz(exp(l-m)/Z, 8,7) -> PV (V async-staged in 64-col halves) ----
  f32x4 zacc[2][4];
  #pragma unroll
  for (int i=0;i<2;++i)
    #pragma unroll
    for (int d=0;d<4;++d) zacc[i][d] = (f32x4){0.f,0.f,0.f,0.f};

  for (int kt=0; kt<8; ++kt){
    #pragma unroll
    for (int c=0;c<4;++c){
      int ch = w*4 + c; int r = ch*8 + srow;
      gll16(KVb + (size_t)(b*1024 + kt*128 + r)*2048 + h*64 + scol, Ks + ch*1024);
    }
    // stage V half 0 (cols kt*128 .. +63): pre-swizzled source, linear LDS dest (rule 21)
    #pragma unroll
    for (int j=0;j<2;++j){
      int cc = j*256 + tid;                 // chunk 0..511
      int row = cc >> 3, s16 = cc & 7;
      int col16 = s16 ^ (row & 7);
      gll16(Vg + (size_t)row*1024 + kt*128 + col16*8, Vs + cc*16);
    }
    __syncthreads();
    f32x4 s[2][8];
    compute_s(Qs, Ks, w, mrow, kg, swz, s);
    #pragma unroll
    for (int i=0;i<2;++i){
      #pragma unroll
      for (int r=0;r<4;++r){
        float Mi = m[i][r], zz = Z[i][r];
        int prow = w*32 + i*16 + 4*kg + r;
        int sw2 = (prow & 7) << 4;
        #pragma unroll
        for (int jf=0;jf<8;++jf){
          float li = clampf(rintf(s[i][jf][r]*2.f), -128.f, 127.f);
          float e = exp_t[(int)(Mi - li)];
          float p = e / zz;                                  // exact div (matches reference bits)
          float pi = fminf(rintf(p*128.f), 127.f);
          *(u16*)(Ps + prow*256 + (((jf*16 + mrow)*2) ^ sw2)) = bfbits(pi*0.0078125f);
        }
      }
    }
    // PV half 0: ms = 0,1 (each wave consumes only its own 32 P rows; Vs swizzled read)
    #pragma unroll
    for (int msh=0; msh<2; ++msh){
      const int ms = msh;
      const int cbp = (64*ms + 16*kg) ^ swz;
      short8 pa0 = *(const short8*)(Ps + (w*32 +  0 + mrow)*256 + cbp);
      short8 pa1 = *(const short8*)(Ps + (w*32 + 16 + mrow)*256 + cbp);
      #pragma unroll
      for (int df=0; df<4; ++df){
        int vrow = df*16 + mrow;
        short8 vb = *(const short8*)(Vs + vrow*128 + (((msh*4 + kg) ^ (vrow & 7)) << 4));
        zacc[0][df] = __builtin_amdgcn_mfma_f32_16x16x32_bf16(pa0, vb, zacc[0][df], 0, 0, 0);
        zacc[1][df] = __builtin_amdgcn_mfma_f32_16x16x32_bf16(pa1, vb, zacc[1][df], 0, 0, 0);
      }
    }
    __syncthreads();
    // stage V half 1 (cols kt*128+64 .. +127)
    #pragma unroll
    for (int j=0;j<2;++j){
      int cc = j*256 + tid;
      int row = cc >> 3, s16 = cc & 7;
      int col16 = s16 ^ (row & 7);
      gll16(Vg + (size_t)row*1024 + kt*128 + 64 + col16*8, Vs + cc*16);
    }
    __syncthreads();
    // PV half 1: ms = 2,3
    #pragma unroll
    for (int msh=0; msh<2; ++msh){
      const int ms = 2 + msh;
      const int cbp = (64*ms + 16*kg) ^ swz;
      short8 pa0 = *(const short8*)(Ps + (w*32 +  0 + mrow)*256 + cbp);
      short8 pa1 = *(const short8*)(Ps + (w*32 + 16 + mrow)*256 + cbp);
      #pragma unroll
      for (int df=0; df<4; ++df){
        int vrow = df*16 + mrow;
        short8 vb = *(const short8*)(Vs + vrow*128 + (((msh*4 + kg) ^ (vrow & 7)) << 4));
        zacc[0][df] = __builtin_amdgcn_mfma_f32_16x16x32_bf16(pa0, vb, zacc[0][df], 0, 0, 0);
        zacc[1][df] = __builtin_amdgcn_mfma_f32_16x16x32_bf16(pa1, vb, zacc[1][df], 0, 0, 0);
      }
    }
    __syncthreads();
  }

  // epilogue: z quantized (8,4) bf16, layout [b,n, h*64+d]
  #pragma unroll
  for (int i=0;i<2;++i){
    #pragma unroll
    for (int df=0; df<4; ++df){
      #pragma unroll
      for (int r=0;r<4;++r){
        int row = qt*128 + w*32 + i*16 + 4*kg + r;
        int col = df*16 + mrow;
        zq[((size_t)b*1024 + row)*1024 + h*64 + col] = bfbits(qz44v(zacc[i][df][r]));
      }
    }
  }
}

// ---------------- launcher ----------------
extern "C" void kernel_launch(void* const* d_in, const int* in_sizes, int n_in,
                              void* d_out, int out_size, void* d_ws, size_t ws_size,
                              hipStream_t stream) {
  const float* x      = (const float*)d_in[0];
  const float* q_w    = (const float*)d_in[1];
  const float* kv_w   = (const float*)d_in[2];
  const float* proj_w = (const float*)d_in[3];
  const float* proj_b = (const float*)d_in[4];
  const float* fc1_w  = (const float*)d_in[5];
  const float* fc1_b  = (const float*)d_in[6];
  const float* fc2_w  = (const float*)d_in[7];
  const float* fc2_b  = (const float*)d_in[8];
  const float* aff1_w = (const float*)d_in[9];
  const float* aff1_b = (const float*)d_in[10];
  const float* aff2_w = (const float*)d_in[11];
  const float* aff2_b = (const float*)d_in[12];

  char* ws = (char*)d_ws;
  const size_t MB = 1u << 20;
  u16*   wq_q  = (u16*)(ws + 0*MB);     // 2MB
  u16*   wq_kv = (u16*)(ws + 2*MB);     // 4MB
  u16*   wq_pj = (u16*)(ws + 6*MB);     // 2MB
  u16*   wq_f1 = (u16*)(ws + 8*MB);     // 8MB
  u16*   wq_f2 = (u16*)(ws + 16*MB);    // 8MB
  float* x1    = (float*)(ws + 24*MB);  // 16MB fp32
  u16*   h1q   = (u16*)(ws + 40*MB);    // 8MB  (reused as zq)
  u16*   Qbuf  = (u16*)(ws + 48*MB);    // 8MB  (reused as h2q)
  u16*   KVb   = (u16*)(ws + 56*MB);    // 16MB
  u16*   VT    = (u16*)(ws + 72*MB);    // 8MB
  u16*   mq    = (u16*)(ws + 56*MB);    // 32MB, overlaps KVb+VT (dead by fc1)
  u16*   zq    = h1q;
  u16*   h2q   = Qbuf;

  // quantize all weights, one launch
  kquantw5<<<12288, 256, 0, stream>>>(q_w, wq_q, kv_w, wq_kv, proj_w, wq_pj,
                                      fc1_w, wq_f1, fc2_w, wq_f2);

  // attention branch
  kaffine<<<4096, 256, 0, stream>>>(x, aff1_w, aff1_b, h1q, 4096*1024);
  kgemm64<0><<<dim3(16,32), 256, 0, stream>>>(h1q, wq_q,  nullptr, nullptr, Qbuf, nullptr, 4096, 1024, 1024);
  kgemm<0><<<dim3(16,32),  256, 0, stream>>>(h1q, wq_kv, nullptr, nullptr, KVb,  nullptr, 4096, 2048, 1024);
  ktransv<<<dim3(16,64), 256, 0, stream>>>(KVb, VT);
  kattn<<<dim3(8,64), 256, 0, stream>>>(Qbuf, KVb, VT, zq);
  kgemm64<1><<<dim3(16,32), 256, 0, stream>>>(zq, wq_pj, proj_b, x, nullptr, x1, 4096, 1024, 1024);

  // mlp branch
  kaffine<<<4096, 256, 0, stream>>>(x1, aff2_w, aff2_b, h2q, 4096*1024);
  kgemm<2><<<dim3(32,32), 256, 0, stream>>>(h2q, wq_f1, fc1_b, nullptr, mq, nullptr, 4096, 4096, 1024);
  kgemm64<3><<<dim3(16,32), 256, 0, stream>>>(mq, wq_f2, fc2_b, x1, nullptr, (float*)d_out, 4096, 1024, 4096);
}

// Round 12
// 382.646 us; speedup vs baseline: 1.1923x; 1.0931x over previous
//
#include <hip/hip_runtime.h>

typedef unsigned short u16;
typedef __attribute__((ext_vector_type(4))) float f32x4;
typedef __attribute__((ext_vector_type(8))) short short8;
typedef __attribute__((ext_vector_type(4))) unsigned short u16x4;
typedef __attribute__((ext_vector_type(8))) unsigned short u16x8;

__device__ __forceinline__ float clampf(float x, float lo, float hi){ return fminf(fmaxf(x, lo), hi); }
__device__ __forceinline__ float qz44i(float x){ return clampf(rintf(x*16.f), -128.f, 127.f); }
__device__ __forceinline__ float qz44v(float x){ return qz44i(x)*0.0625f; }
__device__ __forceinline__ float qz87v(float x){ return clampf(rintf(x*128.f), -128.f, 127.f)*0.0078125f; }
__device__ __forceinline__ u16 bfbits(float f){ return (u16)(__float_as_uint(f) >> 16); }

__device__ __forceinline__ void gll16(const void* g, void* l){
  __builtin_amdgcn_global_load_lds((const __attribute__((address_space(1))) void*)g,
                                   (__attribute__((address_space(3))) void*)l, 16, 0, 0);
}

// ---------------- weight quantize (all 5 weights, one launch): fp32 -> qz(.,8,7) bf16 ----------------
__global__ __launch_bounds__(256) void kquantw5(const float* __restrict__ w0, u16* __restrict__ o0,
                                                const float* __restrict__ w1, u16* __restrict__ o1,
                                                const float* __restrict__ w2, u16* __restrict__ o2,
                                                const float* __restrict__ w3, u16* __restrict__ o3,
                                                const float* __restrict__ w4, u16* __restrict__ o4){
  int v = blockIdx.x*256 + threadIdx.x;
  const float* w; u16* o; int base;
  if      (v <  262144){ w = w0; o = o0; base = 0;       }
  else if (v <  786432){ w = w1; o = o1; base = 262144;  }
  else if (v < 1048576){ w = w2; o = o2; base = 786432;  }
  else if (v < 2097152){ w = w3; o = o3; base = 1048576; }
  else                 { w = w4; o = o4; base = 2097152; }
  int i = (v - base)*4;
  float4 val = *(const float4*)(w + i);
  u16x4 r;
  r.x = bfbits(qz87v(val.x)); r.y = bfbits(qz87v(val.y));
  r.z = bfbits(qz87v(val.z)); r.w = bfbits(qz87v(val.w));
  *(u16x4*)(o + i) = r;
}

// ---------------- affine + quantize ----------------
__global__ __launch_bounds__(256) void kaffine(const float* __restrict__ x, const float* __restrict__ aw,
                                               const float* __restrict__ ab, u16* __restrict__ o, int n){
  int i = (blockIdx.x*256 + threadIdx.x)*4;
  if (i >= n) return;
  float awv = qz44v(aw[0]);
  float abi = qz44i(ab[0]);
  float4 v = *(const float4*)(x + i);
  float in[4] = {v.x, v.y, v.z, v.w};
  u16x4 r;
  #pragma unroll
  for (int k=0;k<4;++k){
    float t  = qz44v(in[k]) * awv;
    float hi = clampf(qz44i(t) + abi, -128.f, 127.f);
    ((u16*)&r)[k] = bfbits(hi*0.0625f);
  }
  *(u16x4*)(o + i) = r;
}

// ---------------- V transpose ----------------
__global__ __launch_bounds__(256) void ktransv(const u16* __restrict__ KVb, u16* __restrict__ VT){
  __shared__ u16 t[64][72];
  int nt = blockIdx.x;
  int bh = blockIdx.y;
  int b = bh >> 4, h = bh & 15;
  int tid = threadIdx.x;
  int nl = tid >> 2, d0 = (tid & 3)*16;
  const u16* src = KVb + (size_t)(b*1024 + nt*64 + nl)*2048 + 1024 + h*64 + d0;
  u16x8 v0 = *(const u16x8*)(src);
  u16x8 v1 = *(const u16x8*)(src + 8);
  #pragma unroll
  for (int k=0;k<8;++k) t[nl][d0+k]   = ((u16*)&v0)[k];
  #pragma unroll
  for (int k=0;k<8;++k) t[nl][d0+8+k] = ((u16*)&v1)[k];
  __syncthreads();
  int dl = tid >> 2, n0 = (tid & 3)*16;
  u16x8 o0, o1;
  #pragma unroll
  for (int k=0;k<8;++k) ((u16*)&o0)[k] = t[n0+k][dl];
  #pragma unroll
  for (int k=0;k<8;++k) ((u16*)&o1)[k] = t[n0+8+k][dl];
  u16* dst = VT + (size_t)bh*65536 + (size_t)dl*1024 + nt*64 + n0;
  *(u16x8*)(dst)     = o0;
  *(u16x8*)(dst + 8) = o1;
}

// ---------------- GEMM 128x128 ----------------
template<int EPI>
__global__ __launch_bounds__(256) void kgemm(
    const u16* __restrict__ A, const u16* __restrict__ Bw,
    const float* __restrict__ bias, const float* __restrict__ extra,
    u16* __restrict__ outB, float* __restrict__ outF,
    int M, int N, int K)
{
  __shared__ char As[128*64*2];
  __shared__ char Bs[128*64*2];
  const int tid = threadIdx.x, lane = tid & 63, w = tid >> 6;
  const int bm = blockIdx.y*128, bn = blockIdx.x*128;
  const int wr = (w>>1)*64, wc = (w&1)*64;
  const int srow = lane>>3;
  const int scol = (((lane&7) ^ srow) & 7)*8;
  const int mrow = lane & 15, kg = lane >> 4, swz = (lane & 7) << 4;

  const u16* Ab = A  + (size_t)bm*K;
  const u16* Bb = Bw + (size_t)bn*K;

  f32x4 acc[4][4];
  #pragma unroll
  for (int i=0;i<4;++i)
    #pragma unroll
    for (int j=0;j<4;++j) acc[i][j] = (f32x4){0.f,0.f,0.f,0.f};

  for (int k0 = 0; k0 < K; k0 += 64){
    #pragma unroll
    for (int c=0;c<4;++c){
      int ch = w*4 + c;
      int row = ch*8 + srow;
      gll16(Ab + (size_t)row*K + k0 + scol, As + ch*1024);
      gll16(Bb + (size_t)row*K + k0 + scol, Bs + ch*1024);
    }
    __syncthreads();
    #pragma unroll
    for (int ks=0; ks<2; ++ks){
      const int cb = (64*ks + 16*kg) ^ swz;
      short8 av[4], bv[4];
      #pragma unroll
      for (int i=0;i<4;++i) av[i] = *(const short8*)(As + (wr + i*16 + mrow)*128 + cb);
      #pragma unroll
      for (int j=0;j<4;++j) bv[j] = *(const short8*)(Bs + (wc + j*16 + mrow)*128 + cb);
      #pragma unroll
      for (int i=0;i<4;++i)
        #pragma unroll
        for (int j=0;j<4;++j)
          acc[i][j] = __builtin_amdgcn_mfma_f32_16x16x32_bf16(av[i], bv[j], acc[i][j], 0, 0, 0);
    }
    __syncthreads();
  }

  #pragma unroll
  for (int i=0;i<4;++i){
    #pragma unroll
    for (int j=0;j<4;++j){
      #pragma unroll
      for (int r=0;r<4;++r){
        int row = bm + wr + i*16 + 4*kg + r;
        int col = bn + wc + j*16 + mrow;
        float y = acc[i][j][r];
        size_t idx = (size_t)row*N + col;
        if (EPI == 0){
          outB[idx] = bfbits(qz44v(y));
        } else if (EPI == 1){
          y += qz87v(bias[col]);
          outF[idx] = qz44v(extra[idx]) + qz44v(y);
        } else if (EPI == 2){
          y += qz87v(bias[col]);
          y = fmaxf(y, 0.f);
          outB[idx] = bfbits(qz44v(y));
        } else {
          y += qz87v(bias[col]);
          outF[idx] = qz44v(extra[idx]) + qz44v(y);
        }
      }
    }
  }
}

// ---------------- GEMM 128x64 ----------------
template<int EPI>
__global__ __launch_bounds__(256) void kgemm64(
    const u16* __restrict__ A, const u16* __restrict__ Bw,
    const float* __restrict__ bias, const float* __restrict__ extra,
    u16* __restrict__ outB, float* __restrict__ outF,
    int M, int N, int K)
{
  __shared__ char As[128*64*2];   // 16KB
  __shared__ char Bs[64*64*2];    // 8KB
  const int tid = threadIdx.x, lane = tid & 63, w = tid >> 6;
  const int bm = blockIdx.y*128, bn = blockIdx.x*64;
  const int wr = w*32;
  const int srow = lane>>3;
  const int scol = (((lane&7) ^ srow) & 7)*8;
  const int mrow = lane & 15, kg = lane >> 4, swz = (lane & 7) << 4;

  const u16* Ab = A  + (size_t)bm*K;
  const u16* Bb = Bw + (size_t)bn*K;

  f32x4 acc[2][4];
  #pragma unroll
  for (int i=0;i<2;++i)
    #pragma unroll
    for (int j=0;j<4;++j) acc[i][j] = (f32x4){0.f,0.f,0.f,0.f};

  for (int k0 = 0; k0 < K; k0 += 64){
    #pragma unroll
    for (int c=0;c<4;++c){
      int ch = w*4 + c;
      int row = ch*8 + srow;
      gll16(Ab + (size_t)row*K + k0 + scol, As + ch*1024);
    }
    #pragma unroll
    for (int c=0;c<2;++c){
      int ch = w*2 + c;
      int row = ch*8 + srow;
      gll16(Bb + (size_t)row*K + k0 + scol, Bs + ch*1024);
    }
    __syncthreads();
    #pragma unroll
    for (int ks=0; ks<2; ++ks){
      const int cb = (64*ks + 16*kg) ^ swz;
      short8 av[2], bv[4];
      #pragma unroll
      for (int i=0;i<2;++i) av[i] = *(const short8*)(As + (wr + i*16 + mrow)*128 + cb);
      #pragma unroll
      for (int j=0;j<4;++j) bv[j] = *(const short8*)(Bs + (j*16 + mrow)*128 + cb);
      #pragma unroll
      for (int i=0;i<2;++i)
        #pragma unroll
        for (int j=0;j<4;++j)
          acc[i][j] = __builtin_amdgcn_mfma_f32_16x16x32_bf16(av[i], bv[j], acc[i][j], 0, 0, 0);
    }
    __syncthreads();
  }

  #pragma unroll
  for (int i=0;i<2;++i){
    #pragma unroll
    for (int j=0;j<4;++j){
      #pragma unroll
      for (int r=0;r<4;++r){
        int row = bm + wr + i*16 + 4*kg + r;
        int col = bn + j*16 + mrow;
        float y = acc[i][j][r];
        size_t idx = (size_t)row*N + col;
        if (EPI == 0){
          outB[idx] = bfbits(qz44v(y));
        } else if (EPI == 1){
          y += qz87v(bias[col]);
          outF[idx] = qz44v(extra[idx]) + qz44v(y);
        } else if (EPI == 2){
          y += qz87v(bias[col]);
          y = fmaxf(y, 0.f);
          outB[idx] = bfbits(qz44v(y));
        } else {
          y += qz87v(bias[col]);
          outF[idx] = qz44v(extra[idx]) + qz44v(y);
        }
      }
    }
  }
}

// ---------------- fused quantized attention ----------------
// Q-frags in registers, double-buffered K tiles, LUT exp, per-row reciprocal scale.
__device__ __forceinline__ void compute_s_reg(const short8 (&qa)[2][2], const char* Ks,
                                              int mrow, int kg, int swz, f32x4 (&s)[2][8]){
  #pragma unroll
  for (int i=0;i<2;++i)
    #pragma unroll
    for (int jf=0;jf<8;++jf) s[i][jf] = (f32x4){0.f,0.f,0.f,0.f};
  #pragma unroll
  for (int jf=0;jf<8;++jf){
    short8 b0 = *(const short8*)(Ks + (jf*16 + mrow)*128 + ((16*kg) ^ swz));
    short8 b1 = *(const short8*)(Ks + (jf*16 + mrow)*128 + ((64 + 16*kg) ^ swz));
    #pragma unroll
    for (int i=0;i<2;++i){
      s[i][jf] = __builtin_amdgcn_mfma_f32_16x16x32_bf16(qa[i][0], b0, s[i][jf], 0, 0, 0);
      s[i][jf] = __builtin_amdgcn_mfma_f32_16x16x32_bf16(qa[i][1], b1, s[i][jf], 0, 0, 0);
    }
  }
}

__global__ __launch_bounds__(256, 4) void kattn(const u16* __restrict__ Qb, const u16* __restrict__ KVb,
                                                const u16* __restrict__ VT, u16* __restrict__ zq)
{
  __shared__ char KsA[128*128];   // 16KB : K buffer 0
  __shared__ char KsB[128*128];   // 16KB : K buffer 1 (also initial Q staging)
  __shared__ char Ps[128*256];    // 32KB
  __shared__ char Vs[64*128];     // 8KB : half of a V^T kt-tile
  __shared__ float exp_t[256];    // 1KB
  const int tid = threadIdx.x, lane = tid & 63, w = tid >> 6;
  const int qt = blockIdx.x, bh = blockIdx.y;
  const int b = bh >> 4, h = bh & 15;
  const int srow = lane >> 3;
  const int scol = (((lane&7) ^ srow) & 7)*8;
  const int mrow = lane & 15, kg = lane >> 4, swz = (lane & 7) << 4;
  const size_t q0 = (size_t)(b*1024 + qt*128);
  const u16* Vg = VT + (size_t)bh*65536;
  const u16* Kg = KVb + (size_t)(b*1024)*2048 + h*64;

  exp_t[tid & 255] = expf(-(float)(tid & 255) * 0.0625f);

  // stage Q into KsB, read fragments to registers (invariant across kt)
  #pragma unroll
  for (int c=0;c<4;++c){
    int ch = w*4 + c; int r = ch*8 + srow;
    gll16(Qb + (q0 + r)*1024 + h*64 + scol, KsB + ch*1024);
  }
  __syncthreads();                 // Q staged + exp_t visible
  short8 qa[2][2];
  #pragma unroll
  for (int i=0;i<2;++i)
    #pragma unroll
    for (int ks=0;ks<2;++ks)
      qa[i][ks] = *(const short8*)(KsB + (w*32 + i*16 + mrow)*128 + ((64*ks + 16*kg) ^ swz));
  __syncthreads();                 // all Q-frag reads done before KsB reuse

  float m[2][4], Z[2][4];
  #pragma unroll
  for (int i=0;i<2;++i)
    #pragma unroll
    for (int r=0;r<4;++r){ m[i][r] = -128.f; Z[i][r] = 0.f; }

  // prologue: stage K(0) -> KsA
  #pragma unroll
  for (int c=0;c<4;++c){
    int ch = w*4 + c; int r = ch*8 + srow;
    gll16(Kg + (size_t)r*2048 + scol, KsA + ch*1024);
  }

  // ---- pass 1: row max + denom (K double-buffered) ----
  for (int kt=0; kt<8; ++kt){
    char* cur = (kt&1) ? KsB : KsA;
    char* nxt = (kt&1) ? KsA : KsB;
    __syncthreads();               // K(kt) landed; all waves past K(kt-1) buffer
    if (kt < 7){
      #pragma unroll
      for (int c=0;c<4;++c){
        int ch = w*4 + c; int r = ch*8 + srow;
        gll16(Kg + (size_t)((kt+1)*128 + r)*2048 + scol, nxt + ch*1024);
      }
    }
    f32x4 s[2][8];
    compute_s_reg(qa, cur, mrow, kg, swz, s);
    #pragma unroll
    for (int i=0;i<2;++i){
      #pragma unroll
      for (int r=0;r<4;++r){
        float li[8];
        float tm = -128.f;
        #pragma unroll
        for (int jf=0;jf<8;++jf){
          li[jf] = clampf(rintf(s[i][jf][r]*2.f), -128.f, 127.f);
          tm = fmaxf(tm, li[jf]);
        }
        #pragma unroll
        for (int off=1; off<16; off<<=1) tm = fmaxf(tm, __shfl_xor(tm, off));
        float ts = 0.f;
        #pragma unroll
        for (int jf=0;jf<8;++jf) ts += exp_t[(int)(tm - li[jf])];
        #pragma unroll
        for (int off=1; off<16; off<<=1) ts += __shfl_xor(ts, off);
        float mo = m[i][r];
        float mn = fmaxf(mo, tm);
        Z[i][r] = Z[i][r]*exp_t[(int)(mn - mo)] + ts*exp_t[(int)(mn - tm)];
        m[i][r] = mn;
      }
    }
  }

  // ---- pass 2: P = qz(exp(l-m)*srow) -> PV ----
  f32x4 zacc[2][4];
  #pragma unroll
  for (int i=0;i<2;++i)
    #pragma unroll
    for (int d=0;d<4;++d) zacc[i][d] = (f32x4){0.f,0.f,0.f,0.f};

  // prologue: stage K(0)->KsA and V half0(0)->Vs (KsA/Vs free: all waves past pass-1 kt=6/untouched)
  #pragma unroll
  for (int c=0;c<4;++c){
    int ch = w*4 + c; int r = ch*8 + srow;
    gll16(Kg + (size_t)r*2048 + scol, KsA + ch*1024);
  }
  #pragma unroll
  for (int j=0;j<2;++j){
    int cc = j*256 + tid;
    int row = cc >> 3, s16 = cc & 7;
    int col16 = s16 ^ (row & 7);
    gll16(Vg + (size_t)row*1024 + col16*8, Vs + cc*16);
  }

  for (int kt=0; kt<8; ++kt){
    char* cur = (kt&1) ? KsB : KsA;
    char* nxt = (kt&1) ? KsA : KsB;
    __syncthreads();               // K(kt) + V half0(kt) landed; all past prior iter
    if (kt < 7){
      #pragma unroll
      for (int c=0;c<4;++c){
        int ch = w*4 + c; int r = ch*8 + srow;
        gll16(Kg + (size_t)((kt+1)*128 + r)*2048 + scol, nxt + ch*1024);
      }
    }
    f32x4 s[2][8];
    compute_s_reg(qa, cur, mrow, kg, swz, s);
    #pragma unroll
    for (int i=0;i<2;++i){
      #pragma unroll
      for (int r=0;r<4;++r){
        float Mi = m[i][r];
        float srw = 128.f / Z[i][r];          // one div per row (ulp-safe: see Z-order argument)
        int prow = w*32 + i*16 + 4*kg + r;
        int sw2 = (prow & 7) << 4;
        #pragma unroll
        for (int jf=0;jf<8;++jf){
          float li = clampf(rintf(s[i][jf][r]*2.f), -128.f, 127.f);
          float e = exp_t[(int)(Mi - li)];
          float pi = fminf(rintf(e*srw), 127.f);
          *(u16*)(Ps + prow*256 + (((jf*16 + mrow)*2) ^ sw2)) = bfbits(pi*0.0078125f);
        }
      }
    }
    // PV half 0 (keys 0..63 of tile; same-wave P rows)
    #pragma unroll
    for (int msh=0; msh<2; ++msh){
      const int cbp = (64*msh + 16*kg) ^ swz;
      short8 pa0 = *(const short8*)(Ps + (w*32 +  0 + mrow)*256 + cbp);
      short8 pa1 = *(const short8*)(Ps + (w*32 + 16 + mrow)*256 + cbp);
      #pragma unroll
      for (int df=0; df<4; ++df){
        int vrow = df*16 + mrow;
        short8 vb = *(const short8*)(Vs + vrow*128 + (((msh*4 + kg) ^ (vrow & 7)) << 4));
        zacc[0][df] = __builtin_amdgcn_mfma_f32_16x16x32_bf16(pa0, vb, zacc[0][df], 0, 0, 0);
        zacc[1][df] = __builtin_amdgcn_mfma_f32_16x16x32_bf16(pa1, vb, zacc[1][df], 0, 0, 0);
      }
    }
    __syncthreads();               // all waves done with V half0
    #pragma unroll
    for (int j=0;j<2;++j){
      int cc = j*256 + tid;
      int row = cc >> 3, s16 = cc & 7;
      int col16 = s16 ^ (row & 7);
      gll16(Vg + (size_t)row*1024 + kt*128 + 64 + col16*8, Vs + cc*16);
    }
    __syncthreads();               // V half1 landed
    // PV half 1 (keys 64..127)
    #pragma unroll
    for (int msh=0; msh<2; ++msh){
      const int cbp = (64*(2+msh) + 16*kg) ^ swz;
      short8 pa0 = *(const short8*)(Ps + (w*32 +  0 + mrow)*256 + cbp);
      short8 pa1 = *(const short8*)(Ps + (w*32 + 16 + mrow)*256 + cbp);
      #pragma unroll
      for (int df=0; df<4; ++df){
        int vrow = df*16 + mrow;
        short8 vb = *(const short8*)(Vs + vrow*128 + (((msh*4 + kg) ^ (vrow & 7)) << 4));
        zacc[0][df] = __builtin_amdgcn_mfma_f32_16x16x32_bf16(pa0, vb, zacc[0][df], 0, 0, 0);
        zacc[1][df] = __builtin_amdgcn_mfma_f32_16x16x32_bf16(pa1, vb, zacc[1][df], 0, 0, 0);
      }
    }
    if (kt < 7){
      __syncthreads();             // all waves done with V half1
      #pragma unroll
      for (int j=0;j<2;++j){
        int cc = j*256 + tid;
        int row = cc >> 3, s16 = cc & 7;
        int col16 = s16 ^ (row & 7);
        gll16(Vg + (size_t)row*1024 + (kt+1)*128 + col16*8, Vs + cc*16);
      }
    }
  }

  // epilogue: z quantized (8,4) bf16, layout [b,n, h*64+d]
  #pragma unroll
  for (int i=0;i<2;++i){
    #pragma unroll
    for (int df=0; df<4; ++df){
      #pragma unroll
      for (int r=0;r<4;++r){
        int row = qt*128 + w*32 + i*16 + 4*kg + r;
        int col = df*16 + mrow;
        zq[((size_t)b*1024 + row)*1024 + h*64 + col] = bfbits(qz44v(zacc[i][df][r]));
      }
    }
  }
}

// ---------------- launcher ----------------
extern "C" void kernel_launch(void* const* d_in, const int* in_sizes, int n_in,
                              void* d_out, int out_size, void* d_ws, size_t ws_size,
                              hipStream_t stream) {
  const float* x      = (const float*)d_in[0];
  const float* q_w    = (const float*)d_in[1];
  const float* kv_w   = (const float*)d_in[2];
  const float* proj_w = (const float*)d_in[3];
  const float* proj_b = (const float*)d_in[4];
  const float* fc1_w  = (const float*)d_in[5];
  const float* fc1_b  = (const float*)d_in[6];
  const float* fc2_w  = (const float*)d_in[7];
  const float* fc2_b  = (const float*)d_in[8];
  const float* aff1_w = (const float*)d_in[9];
  const float* aff1_b = (const float*)d_in[10];
  const float* aff2_w = (const float*)d_in[11];
  const float* aff2_b = (const float*)d_in[12];

  char* ws = (char*)d_ws;
  const size_t MB = 1u << 20;
  u16*   wq_q  = (u16*)(ws + 0*MB);
  u16*   wq_kv = (u16*)(ws + 2*MB);
  u16*   wq_pj = (u16*)(ws + 6*MB);
  u16*   wq_f1 = (u16*)(ws + 8*MB);
  u16*   wq_f2 = (u16*)(ws + 16*MB);
  float* x1    = (float*)(ws + 24*MB);
  u16*   h1q   = (u16*)(ws + 40*MB);
  u16*   Qbuf  = (u16*)(ws + 48*MB);
  u16*   KVb   = (u16*)(ws + 56*MB);
  u16*   VT    = (u16*)(ws + 72*MB);
  u16*   mq    = (u16*)(ws + 56*MB);
  u16*   zq    = h1q;
  u16*   h2q   = Qbuf;

  kquantw5<<<12288, 256, 0, stream>>>(q_w, wq_q, kv_w, wq_kv, proj_w, wq_pj,
                                      fc1_w, wq_f1, fc2_w, wq_f2);

  kaffine<<<4096, 256, 0, stream>>>(x, aff1_w, aff1_b, h1q, 4096*1024);
  kgemm64<0><<<dim3(16,32), 256, 0, stream>>>(h1q, wq_q,  nullptr, nullptr, Qbuf, nullptr, 4096, 1024, 1024);
  kgemm<0><<<dim3(16,32),  256, 0, stream>>>(h1q, wq_kv, nullptr, nullptr, KVb,  nullptr, 4096, 2048, 1024);
  ktransv<<<dim3(16,64), 256, 0, stream>>>(KVb, VT);
  kattn<<<dim3(8,64), 256, 0, stream>>>(Qbuf, KVb, VT, zq);
  kgemm64<1><<<dim3(16,32), 256, 0, stream>>>(zq, wq_pj, proj_b, x, nullptr, x1, 4096, 1024, 1024);

  kaffine<<<4096, 256, 0, stream>>>(x1, aff2_w, aff2_b, h2q, 4096*1024);
  kgemm<2><<<dim3(32,32), 256, 0, stream>>>(h2q, wq_f1, fc1_b, nullptr, mq, nullptr, 4096, 4096, 1024);
  kgemm64<3><<<dim3(16,32), 256, 0, stream>>>(mq, wq_f2, fc2_b, x1, nullptr, (float*)d_out, 4096, 1024, 4096);
}